// Round 8
// baseline (1667.247 us; speedup 1.0000x reference)
//
#include <hip/hip_runtime.h>
#include <math.h>

#define EPSV 1e-5f

typedef __attribute__((ext_vector_type(8))) short bf16x8;
typedef __attribute__((ext_vector_type(4))) float f32x4;

// ---- bf16 helpers (round-to-nearest-even pack, bit-shift unpack) ------------------
__device__ __forceinline__ unsigned short f2bf(float f) {
    unsigned u = __float_as_uint(f);
    u += 0x7fffu + ((u >> 16) & 1u);
    return (unsigned short)(u >> 16);
}
__device__ __forceinline__ float bf2f(unsigned short h) {
    return __uint_as_float(((unsigned)h) << 16);
}

// ---------------- prep: ksum, cbi, fragment-packed weights, zero stats -------------
// Fragment packing (for mfma_f32_16x16x32_bf16): frag(nf, ks) is 64 lanes x 8 vals;
// lane l, elem i holds B[k][n] with k = ks*32 + (l>>4)*8 + i, n = nf*16 + (l&15).
// Flat: Bp[((nf*(K/32) + ks)*64 + l)*8 + i]. Same (g,i)->k bijection is used for A
// frags, so the MFMA reduction is exact regardless of HW internal k order.
__global__ __launch_bounds__(256)
void prep_kernel(const float* __restrict__ Wv, const float* __restrict__ Wq,
                 const float* __restrict__ cb, const float* __restrict__ Wout,
                 float* __restrict__ ksum, unsigned short* __restrict__ cbi,
                 unsigned short* __restrict__ Bvp, unsigned short* __restrict__ Bop,
                 unsigned short* __restrict__ Bqh, unsigned short* __restrict__ Bql,
                 float* __restrict__ stats)
{
    const long gid = (long)blockIdx.x * 256 + threadIdx.x;
    // cbi[k][g*8+h]: h<4 -> cb0[k][g*4+h], h>=4 -> cb1[k][g*4+h-4]  (27*512 bf16)
    if (gid < 27 * 512) {
        const int k = (int)(gid >> 9);
        const int r = (int)(gid & 511);
        const int g = r >> 3;
        const int h = r & 7;
        const float v = (h < 4) ? cb[k * 256 + g * 4 + h]
                                : cb[(27 + k) * 256 + g * 4 + (h - 4)];
        cbi[gid] = f2bf(v);
    }
    // Bvp: Wv [128][256], K=128 (4 ksteps), 16 col-frags -> 32768 bf16
    if (gid < 32768) {
        const int i = (int)(gid & 7);
        const int l = (int)((gid >> 3) & 63);
        const int rest = (int)(gid >> 9);
        const int ks = rest & 3, nf = rest >> 2;
        const int k = ks * 32 + ((l >> 4) << 3) + i;
        const int n = nf * 16 + (l & 15);
        Bvp[gid] = f2bf(Wv[k * 256 + n]);
    }
    // Bop: Wout [256][128], K=256 (8 ksteps), 8 col-frags -> 32768 bf16
    if (gid < 32768) {
        const int i = (int)(gid & 7);
        const int l = (int)((gid >> 3) & 63);
        const int rest = (int)(gid >> 9);
        const int ks = rest & 7, nf = rest >> 3;
        const int k = ks * 32 + ((l >> 4) << 3) + i;
        const int n = nf * 16 + (l & 15);
        Bop[gid] = f2bf(Wout[k * 128 + n]);
    }
    // Bqh/Bql: Wq[n][k] split hi/lo, K=128, 2 col-frags (cols >=27 zero) -> 4096 each
    if (gid < 4096) {
        const int i = (int)(gid & 7);
        const int l = (int)((gid >> 3) & 63);
        const int rest = (int)(gid >> 9);
        const int ks = rest & 3, nf = rest >> 2;
        const int k = ks * 32 + ((l >> 4) << 3) + i;
        const int n = nf * 16 + (l & 15);
        const float w = (n < 27) ? Wq[n * 128 + k] : 0.f;
        const unsigned short h = f2bf(w);
        Bqh[gid] = h;
        Bql[gid] = f2bf(w - bf2f(h));
    }
    if (gid < 1024) stats[gid] = 0.f;
    if (gid < 64) {
        float s = 0.f;
        if (gid < 27) { const float* p = cb + gid * 256; for (int c = 0; c < 256; ++c) s += p[c]; }
        else if (gid >= 32 && gid < 59) { const float* p = cb + (27 + (gid - 32)) * 256; for (int c = 0; c < 256; ++c) s += p[c]; }
        ksum[gid] = s;
    }
}

// ---------------- MFMA GEMM: C[M x NC] = A[M x K] @ Bp (fragment-packed) -----------
// Block: 256 thr / 4 waves; tile 128 rows x 64 cols; wave w -> rows w*32..w*32+31.
// A staged to LDS (fp32->bf16 cast if !ABF), padded [128][40] (2-way conflict: free).
template<int K, bool ABF, bool OUTBF>
__global__ __launch_bounds__(256)
void mfma_gemm(const void* __restrict__ Avoid, const unsigned short* __restrict__ Bp,
               unsigned short* __restrict__ Cb, float* __restrict__ Cf, int ldc)
{
    __shared__ unsigned short As[128][40];
    const int tid  = threadIdx.x;
    const int w    = tid >> 6, lane = tid & 63;
    const int r15  = lane & 15, g = lane >> 4;
    const long m0  = (long)blockIdx.y * 128;
    const int n0   = blockIdx.x * 64;
    const int nfrag0 = n0 >> 4;
    const int srow = tid >> 1;
    const int shalf = tid & 1;

    f32x4 acc[2][4];
    #pragma unroll
    for (int a_ = 0; a_ < 2; ++a_)
        #pragma unroll
        for (int b_ = 0; b_ < 4; ++b_) acc[a_][b_] = (f32x4){0.f, 0.f, 0.f, 0.f};

    for (int ks = 0; ks < K / 32; ++ks) {
        const int k0 = ks * 32;
        __syncthreads();
        if constexpr (ABF) {
            const unsigned short* A = (const unsigned short*)Avoid;
            const uint4 v0 = *(const uint4*)(A + (m0 + srow) * K + k0 + shalf * 16);
            const uint4 v1 = *(const uint4*)(A + (m0 + srow) * K + k0 + shalf * 16 + 8);
            *(uint4*)&As[srow][shalf * 16]     = v0;
            *(uint4*)&As[srow][shalf * 16 + 8] = v1;
        } else {
            const float* A = (const float*)Avoid + (m0 + srow) * K + k0 + shalf * 16;
            const float4 f0 = *(const float4*)(A + 0);
            const float4 f1 = *(const float4*)(A + 4);
            const float4 f2 = *(const float4*)(A + 8);
            const float4 f3 = *(const float4*)(A + 12);
            ushort4 h0 = { f2bf(f0.x), f2bf(f0.y), f2bf(f0.z), f2bf(f0.w) };
            ushort4 h1 = { f2bf(f1.x), f2bf(f1.y), f2bf(f1.z), f2bf(f1.w) };
            ushort4 h2 = { f2bf(f2.x), f2bf(f2.y), f2bf(f2.z), f2bf(f2.w) };
            ushort4 h3 = { f2bf(f3.x), f2bf(f3.y), f2bf(f3.z), f2bf(f3.w) };
            *(ushort4*)&As[srow][shalf * 16 + 0]  = h0;
            *(ushort4*)&As[srow][shalf * 16 + 4]  = h1;
            *(ushort4*)&As[srow][shalf * 16 + 8]  = h2;
            *(ushort4*)&As[srow][shalf * 16 + 12] = h3;
        }
        __syncthreads();
        bf16x8 af0 = *(const bf16x8*)&As[w * 32 + r15][g * 8];
        bf16x8 af1 = *(const bf16x8*)&As[w * 32 + 16 + r15][g * 8];
        #pragma unroll
        for (int nf = 0; nf < 4; ++nf) {
            const bf16x8 bf = *(const bf16x8*)(Bp + (((nfrag0 + nf) * (K / 32) + ks) * 64 + lane) * 8);
            acc[0][nf] = __builtin_amdgcn_mfma_f32_16x16x32_bf16(af0, bf, acc[0][nf], 0, 0, 0);
            acc[1][nf] = __builtin_amdgcn_mfma_f32_16x16x32_bf16(af1, bf, acc[1][nf], 0, 0, 0);
        }
    }
    // epilogue: C row = m0 + w*32 + fr*16 + g*4 + r, col = n0 + nf*16 + r15
    #pragma unroll
    for (int fr = 0; fr < 2; ++fr)
        #pragma unroll
        for (int nf = 0; nf < 4; ++nf)
            #pragma unroll
            for (int r = 0; r < 4; ++r) {
                const long row = m0 + w * 32 + fr * 16 + g * 4 + r;
                const int col = n0 + nf * 16 + r15;
                if constexpr (OUTBF) Cb[row * ldc + col] = f2bf(acc[fr][nf][r]);
                else                 Cf[row * ldc + col] = acc[fr][nf][r];
            }
}

// ---------------- MFMA y: y[N,27] = x @ Wq^T via 3-term bf16 split (near-fp32) -----
__global__ __launch_bounds__(256)
void mfma_y(const float* __restrict__ X, const unsigned short* __restrict__ Bqh,
            const unsigned short* __restrict__ Bql, float* __restrict__ y)
{
    __shared__ unsigned short Ah[128][40];
    __shared__ unsigned short Al[128][40];
    const int tid  = threadIdx.x;
    const int w    = tid >> 6, lane = tid & 63;
    const int r15  = lane & 15, g = lane >> 4;
    const long m0  = (long)blockIdx.y * 128;
    const int srow = tid >> 1;
    const int shalf = tid & 1;

    f32x4 acc[2][2];
    #pragma unroll
    for (int a_ = 0; a_ < 2; ++a_)
        #pragma unroll
        for (int b_ = 0; b_ < 2; ++b_) acc[a_][b_] = (f32x4){0.f, 0.f, 0.f, 0.f};

    for (int ks = 0; ks < 4; ++ks) {
        const int k0 = ks * 32;
        __syncthreads();
        {
            const float* A = X + (m0 + srow) * 128 + k0 + shalf * 16;
            float fs[16];
            const float4 f0 = *(const float4*)(A + 0);
            const float4 f1 = *(const float4*)(A + 4);
            const float4 f2 = *(const float4*)(A + 8);
            const float4 f3 = *(const float4*)(A + 12);
            fs[0]=f0.x; fs[1]=f0.y; fs[2]=f0.z; fs[3]=f0.w;
            fs[4]=f1.x; fs[5]=f1.y; fs[6]=f1.z; fs[7]=f1.w;
            fs[8]=f2.x; fs[9]=f2.y; fs[10]=f2.z; fs[11]=f2.w;
            fs[12]=f3.x; fs[13]=f3.y; fs[14]=f3.z; fs[15]=f3.w;
            #pragma unroll
            for (int q4 = 0; q4 < 4; ++q4) {
                ushort4 hq, lq;
                unsigned short h;
                h = f2bf(fs[q4*4+0]); hq.x = h; lq.x = f2bf(fs[q4*4+0] - bf2f(h));
                h = f2bf(fs[q4*4+1]); hq.y = h; lq.y = f2bf(fs[q4*4+1] - bf2f(h));
                h = f2bf(fs[q4*4+2]); hq.z = h; lq.z = f2bf(fs[q4*4+2] - bf2f(h));
                h = f2bf(fs[q4*4+3]); hq.w = h; lq.w = f2bf(fs[q4*4+3] - bf2f(h));
                *(ushort4*)&Ah[srow][shalf * 16 + q4 * 4] = hq;
                *(ushort4*)&Al[srow][shalf * 16 + q4 * 4] = lq;
            }
        }
        __syncthreads();
        bf16x8 ah0 = *(const bf16x8*)&Ah[w * 32 + r15][g * 8];
        bf16x8 ah1 = *(const bf16x8*)&Ah[w * 32 + 16 + r15][g * 8];
        bf16x8 al0 = *(const bf16x8*)&Al[w * 32 + r15][g * 8];
        bf16x8 al1 = *(const bf16x8*)&Al[w * 32 + 16 + r15][g * 8];
        #pragma unroll
        for (int nf = 0; nf < 2; ++nf) {
            const bf16x8 bh = *(const bf16x8*)(Bqh + ((nf * 4 + ks) * 64 + lane) * 8);
            const bf16x8 bl = *(const bf16x8*)(Bql + ((nf * 4 + ks) * 64 + lane) * 8);
            acc[0][nf] = __builtin_amdgcn_mfma_f32_16x16x32_bf16(ah0, bh, acc[0][nf], 0, 0, 0);
            acc[0][nf] = __builtin_amdgcn_mfma_f32_16x16x32_bf16(ah0, bl, acc[0][nf], 0, 0, 0);
            acc[0][nf] = __builtin_amdgcn_mfma_f32_16x16x32_bf16(al0, bh, acc[0][nf], 0, 0, 0);
            acc[1][nf] = __builtin_amdgcn_mfma_f32_16x16x32_bf16(ah1, bh, acc[1][nf], 0, 0, 0);
            acc[1][nf] = __builtin_amdgcn_mfma_f32_16x16x32_bf16(ah1, bl, acc[1][nf], 0, 0, 0);
            acc[1][nf] = __builtin_amdgcn_mfma_f32_16x16x32_bf16(al1, bh, acc[1][nf], 0, 0, 0);
        }
    }
    #pragma unroll
    for (int fr = 0; fr < 2; ++fr)
        #pragma unroll
        for (int nf = 0; nf < 2; ++nf)
            #pragma unroll
            for (int r = 0; r < 4; ++r) {
                const long row = m0 + w * 32 + fr * 16 + g * 4 + r;
                const int col = nf * 16 + r15;
                if (col < 27) y[row * 27 + col] = acc[fr][nf][r];
            }
}

// ---------------- column stats (sum, sumsq) over t1b [N,256] bf16 ------------------
__global__ __launch_bounds__(256)
void stats_t1(const unsigned short* __restrict__ t1b, float* __restrict__ stats)
{
    const int c = threadIdx.x;
    const long r0 = (long)blockIdx.x * 256;
    float s = 0.f, s2 = 0.f;
    #pragma unroll 4
    for (int r = 0; r < 256; ++r) {
        const float v = bf2f(t1b[(r0 + r) * 256 + c]);
        s += v; s2 += v * v;
    }
    atomicAdd(&stats[c], s);
    atomicAdd(&stats[256 + c], s2);
}

// ---------------- q_pre[n] = sum_k y[nbr[n,k], k]; accumulate scalar stats ---------
__global__ __launch_bounds__(256)
void qpre_kernel(const float* __restrict__ y, const int* __restrict__ nbr,
                 float* __restrict__ qpre, float* __restrict__ stats)
{
    __shared__ int snbr[256 * 27];
    __shared__ float red[8];
    const int tid = threadIdx.x;
    const long base = (long)blockIdx.x * 256;
    for (int j = tid; j < 256 * 27; j += 256) snbr[j] = nbr[base * 27 + j];
    __syncthreads();
    float q = 0.f;
    #pragma unroll
    for (int k = 0; k < 27; ++k) {
        const int idx = snbr[tid * 27 + k];
        q += y[(long)idx * 27 + k];
    }
    qpre[base + tid] = q;
    float s = q, s2 = q * q;
    #pragma unroll
    for (int off = 32; off > 0; off >>= 1) {
        s  += __shfl_xor(s, off);
        s2 += __shfl_xor(s2, off);
    }
    const int wid = tid >> 6;
    if ((tid & 63) == 0) { red[wid] = s; red[4 + wid] = s2; }
    __syncthreads();
    if (tid == 0) {
        atomicAdd(&stats[512], red[0] + red[1] + red[2] + red[3]);
        atomicAdd(&stats[513], red[4] + red[5] + red[6] + red[7]);
    }
}

// ---------------- gather/route: EXACT R4 structure (VGPR 40, occ 65%) + cbi --------
// R4 lesson bank: naive load-then-consume loop is what hipcc schedules frugally;
// explicit staging arrays (R5 27-deep, R7 rolling-6) inflate VGPR 3-4x; adding a
// launch-bounds cap on top spills to scratch (R6). Do NOT hand-pipeline this loop.
__global__ __launch_bounds__(256, 4)
void gather_route(const unsigned short* __restrict__ t1b, const float* __restrict__ qpre,
                  const int* __restrict__ nbr, const unsigned short* __restrict__ cbi,
                  const float* __restrict__ ksum, const float* __restrict__ stats,
                  const float* __restrict__ gv, const float* __restrict__ bvp,
                  const float* __restrict__ gq, const float* __restrict__ bq,
                  unsigned short* __restrict__ outpre, float inv_n)
{
    const long p   = (long)((blockIdx.x * 256 + threadIdx.x) >> 6);
    const int lane = threadIdx.x & 63;
    const int c4   = lane * 4;

    // per-lane v-BN affine coeffs (4 channels)
    float a[4], b[4];
    #pragma unroll
    for (int j = 0; j < 4; ++j) {
        const float mu  = stats[c4 + j] * inv_n;
        const float var = stats[256 + c4 + j] * inv_n - mu * mu;
        const float sc  = gv[c4 + j] * rsqrtf(var + EPSV);
        a[j] = sc;
        b[j] = bvp[c4 + j] - mu * sc;
    }
    // choice softmax: lanes 0..26 gather q of neighbors
    float s0 = 0.f, s1 = 0.f;
    int idx = 0;
    {
        const float muq  = stats[512] * inv_n;
        const float varq = stats[513] * inv_n - muq * muq;
        const float aq   = gq[0] * rsqrtf(varq + EPSV);
        const float bqc  = bq[0] - muq * aq;
        if (lane < 27) {
            idx = nbr[p * 27 + lane];
            const float qn = fmaxf(fmaf(qpre[idx], aq, bqc), 0.f);
            s0 = qn * ksum[lane];
            s1 = qn * ksum[32 + lane];
        }
    }
    #pragma unroll
    for (int off = 32; off > 0; off >>= 1) {
        s0 += __shfl_xor(s0, off);
        s1 += __shfl_xor(s1, off);
    }
    const float mm = fmaxf(s0, s1);
    const float e0 = __expf(s0 - mm);
    const float e1 = __expf(s1 - mm);
    const float c0 = e0 / (e0 + e1);
    const float c1 = 1.f - c0;

    float acc0[4] = {0, 0, 0, 0}, acc1[4] = {0, 0, 0, 0};
    #pragma unroll
    for (int k = 0; k < 27; ++k) {
        const int ik = __shfl(idx, k);
        const uint2 uu = *(const uint2*)(t1b + (long)ik * 256 + c4);   // 4 bf16, 8B/lane
        const uint4 w  = *(const uint4*)(cbi + k * 512 + lane * 8);    // w0[4],w1[4] bf16
        const float t0  = __uint_as_float(uu.x << 16);
        const float t1v = __uint_as_float(uu.x & 0xffff0000u);
        const float t2v = __uint_as_float(uu.y << 16);
        const float t3  = __uint_as_float(uu.y & 0xffff0000u);
        const float v0 = fmaxf(fmaf(t0,  a[0], b[0]), 0.f);
        const float v1 = fmaxf(fmaf(t1v, a[1], b[1]), 0.f);
        const float v2 = fmaxf(fmaf(t2v, a[2], b[2]), 0.f);
        const float v3 = fmaxf(fmaf(t3,  a[3], b[3]), 0.f);
        acc0[0] = fmaf(v0, __uint_as_float(w.x << 16),         acc0[0]);
        acc0[1] = fmaf(v1, __uint_as_float(w.x & 0xffff0000u), acc0[1]);
        acc0[2] = fmaf(v2, __uint_as_float(w.y << 16),         acc0[2]);
        acc0[3] = fmaf(v3, __uint_as_float(w.y & 0xffff0000u), acc0[3]);
        acc1[0] = fmaf(v0, __uint_as_float(w.z << 16),         acc1[0]);
        acc1[1] = fmaf(v1, __uint_as_float(w.z & 0xffff0000u), acc1[1]);
        acc1[2] = fmaf(v2, __uint_as_float(w.w << 16),         acc1[2]);
        acc1[3] = fmaf(v3, __uint_as_float(w.w & 0xffff0000u), acc1[3]);
    }
    ushort4 o;
    o.x = f2bf(fmaf(c0, acc0[0], c1 * acc1[0]));
    o.y = f2bf(fmaf(c0, acc0[1], c1 * acc1[1]));
    o.z = f2bf(fmaf(c0, acc0[2], c1 * acc1[2]));
    o.w = f2bf(fmaf(c0, acc0[3], c1 * acc1[3]));
    *(ushort4*)(outpre + p * 256 + c4) = o;
}

// ---------------- column stats over t2 [N,128] -------------------------------------
__global__ __launch_bounds__(128)
void stats_t2(const float* __restrict__ t2, float* __restrict__ stats)
{
    const int c = threadIdx.x;
    const long r0 = (long)blockIdx.x * 128;
    float s = 0.f, s2 = 0.f;
    #pragma unroll 4
    for (int r = 0; r < 128; ++r) {
        const float v = t2[(r0 + r) * 128 + c];
        s += v; s2 += v * v;
    }
    atomicAdd(&stats[544 + c], s);
    atomicAdd(&stats[672 + c], s2);
}

// ---------------- final BN+ReLU+residual (in-place on t2 == d_out) -----------------
__global__ __launch_bounds__(256)
void final_kernel(const float* __restrict__ t2, const float* __restrict__ x,
                  const float* __restrict__ stats,
                  const float* __restrict__ go, const float* __restrict__ bo,
                  float* __restrict__ out, long total4, float inv_n)
{
    const long i = (long)blockIdx.x * 256 + threadIdx.x;
    if (i >= total4) return;
    const int c4 = (int)((i * 4) & 127);
    float a[4], b[4];
    #pragma unroll
    for (int j = 0; j < 4; ++j) {
        const float mu  = stats[544 + c4 + j] * inv_n;
        const float var = stats[672 + c4 + j] * inv_n - mu * mu;
        const float sc  = go[c4 + j] * rsqrtf(var + EPSV);
        a[j] = sc;
        b[j] = bo[c4 + j] - mu * sc;
    }
    const float4 t  = *((const float4*)t2 + i);   // in-place safe
    const float4 xx = *((const float4*)x + i);
    float4 o;
    o.x = fmaxf(fmaf(t.x, a[0], b[0]), 0.f) + xx.x;
    o.y = fmaxf(fmaf(t.y, a[1], b[1]), 0.f) + xx.y;
    o.z = fmaxf(fmaf(t.z, a[2], b[2]), 0.f) + xx.z;
    o.w = fmaxf(fmaf(t.w, a[3], b[3]), 0.f) + xx.w;
    *((float4*)out + i) = o;
}

extern "C" void kernel_launch(void* const* d_in, const int* in_sizes, int n_in,
                              void* d_out, int out_size, void* d_ws, size_t ws_size,
                              hipStream_t stream)
{
    const float* x    = (const float*)d_in[0];
    const int*   nbr  = (const int*)d_in[1];
    const float* Wv   = (const float*)d_in[2];
    const float* gv   = (const float*)d_in[3];
    const float* bv   = (const float*)d_in[4];
    const float* Wq   = (const float*)d_in[5];
    const float* gq   = (const float*)d_in[6];
    const float* bq   = (const float*)d_in[7];
    const float* cb   = (const float*)d_in[8];
    const float* Wout = (const float*)d_in[9];
    const float* go   = (const float*)d_in[10];
    const float* bo   = (const float*)d_in[11];
    float* out = (float*)d_out;
    float* ws  = (float*)d_ws;

    const int N = in_sizes[0] / 128;
    const float inv_n = 1.f / (float)N;

    // workspace (floats): 65536 header + N*(128 + 27 + 1 + 128)  (~149 MB @ N=131072)
    float* ksum  = ws;                                     // 64
    float* stats = ws + 64;                                // 1024
    unsigned short* cbi = (unsigned short*)(ws + 2048);    // 13824 us (6912 fl)
    unsigned short* Bvp = (unsigned short*)(ws + 9216);    // 32768 us (16384 fl)
    unsigned short* Bop = (unsigned short*)(ws + 25600);   // 32768 us (16384 fl)
    unsigned short* Bqh = (unsigned short*)(ws + 41984);   // 4096 us (2048 fl)
    unsigned short* Bql = (unsigned short*)(ws + 44032);   // 4096 us (2048 fl)
    unsigned short* t1b = (unsigned short*)(ws + 65536);   // N*256 bf16
    float* y    = ws + 65536 + (long)N * 128;              // N*27
    float* qpre = y + (long)N * 27;                        // N
    unsigned short* outpre = (unsigned short*)(qpre + N);  // N*256 bf16
    float* t2   = out;                                     // N*128 in d_out

    hipLaunchKernelGGL(prep_kernel, dim3(192), dim3(256), 0, stream,
                       Wv, Wq, cb, Wout, ksum, cbi, Bvp, Bop, Bqh, Bql, stats);
    // t1b = bf16(x) @ Wv  (MFMA, 4 col-tiles of 64)
    mfma_gemm<128, false, true><<<dim3(4, N / 128), dim3(256), 0, stream>>>(
        (const void*)x, Bvp, t1b, (float*)nullptr, 256);
    // y = x @ Wq^T  (MFMA 3-term split, near-fp32)
    mfma_y<<<dim3(1, N / 128), dim3(256), 0, stream>>>(x, Bqh, Bql, y);
    hipLaunchKernelGGL(stats_t1, dim3(N / 256), dim3(256), 0, stream, t1b, stats);
    hipLaunchKernelGGL(qpre_kernel, dim3(N / 256), dim3(256), 0, stream, y, nbr, qpre, stats);
    hipLaunchKernelGGL(gather_route, dim3(N / 4), dim3(256), 0, stream,
                       t1b, qpre, nbr, cbi, ksum, stats, gv, bv, gq, bq, outpre, inv_n);
    // t2 = outpre @ Wout  (MFMA, 2 col-tiles of 64)
    mfma_gemm<256, true, false><<<dim3(2, N / 128), dim3(256), 0, stream>>>(
        (const void*)outpre, Bop, (unsigned short*)nullptr, t2, 128);
    hipLaunchKernelGGL(stats_t2, dim3(N / 128), dim3(128), 0, stream, t2, stats);
    hipLaunchKernelGGL(final_kernel, dim3((unsigned)(((long)N * 128 / 4 + 255) / 256)), dim3(256), 0, stream,
                       t2, x, stats, go, bo, out, (long)N * 128 / 4, inv_n);
}

// Round 9
// 739.922 us; speedup vs baseline: 2.2533x; 2.2533x over previous
//
#include <hip/hip_runtime.h>
#include <math.h>

#define EPSV 1e-5f

typedef __attribute__((ext_vector_type(8))) short bf16x8;
typedef __attribute__((ext_vector_type(4))) float f32x4;

// ---- bf16 helpers (round-to-nearest-even pack, bit-shift unpack) ------------------
__device__ __forceinline__ unsigned short f2bf(float f) {
    unsigned u = __float_as_uint(f);
    u += 0x7fffu + ((u >> 16) & 1u);
    return (unsigned short)(u >> 16);
}
__device__ __forceinline__ float bf2f(unsigned short h) {
    return __uint_as_float(((unsigned)h) << 16);
}

// ---------------- prep: ksum, fragment-packed weights, zero stats ------------------
// Fragment packing (for mfma_f32_16x16x32_bf16): frag(nf, ks) is 64 lanes x 8 vals;
// lane l, elem i holds B[k][n] with k = ks*32 + (l>>4)*8 + i, n = nf*16 + (l&15).
// Same (g,i)->k bijection is used for A frags, so the K-reduction is exact.
__global__ __launch_bounds__(256)
void prep_kernel(const float* __restrict__ Wv, const float* __restrict__ Wq,
                 const float* __restrict__ cb, const float* __restrict__ Wout,
                 float* __restrict__ ksum,
                 unsigned short* __restrict__ Bvp, unsigned short* __restrict__ Bop,
                 unsigned short* __restrict__ Bqh, unsigned short* __restrict__ Bql,
                 float* __restrict__ stats)
{
    const long gid = (long)blockIdx.x * 256 + threadIdx.x;
    // Bvp: Wv [128][256], K=128 (4 ksteps), 16 col-frags -> 32768 bf16
    if (gid < 32768) {
        const int i = (int)(gid & 7);
        const int l = (int)((gid >> 3) & 63);
        const int rest = (int)(gid >> 9);
        const int ks = rest & 3, nf = rest >> 2;
        const int k = ks * 32 + ((l >> 4) << 3) + i;
        const int n = nf * 16 + (l & 15);
        Bvp[gid] = f2bf(Wv[k * 256 + n]);
    }
    // Bop: Wout [256][128], K=256 (8 ksteps), 8 col-frags -> 32768 bf16
    if (gid < 32768) {
        const int i = (int)(gid & 7);
        const int l = (int)((gid >> 3) & 63);
        const int rest = (int)(gid >> 9);
        const int ks = rest & 7, nf = rest >> 3;
        const int k = ks * 32 + ((l >> 4) << 3) + i;
        const int n = nf * 16 + (l & 15);
        Bop[gid] = f2bf(Wout[k * 128 + n]);
    }
    // Bqh/Bql: Wq[n][k] split hi/lo, K=128, 2 col-frags (cols >=27 zero) -> 4096 each
    if (gid < 4096) {
        const int i = (int)(gid & 7);
        const int l = (int)((gid >> 3) & 63);
        const int rest = (int)(gid >> 9);
        const int ks = rest & 3, nf = rest >> 2;
        const int k = ks * 32 + ((l >> 4) << 3) + i;
        const int n = nf * 16 + (l & 15);
        const float w = (n < 27) ? Wq[n * 128 + k] : 0.f;
        const unsigned short h = f2bf(w);
        Bqh[gid] = h;
        Bql[gid] = f2bf(w - bf2f(h));
    }
    if (gid < 1024) stats[gid] = 0.f;
    if (gid < 64) {
        float s = 0.f;
        if (gid < 27) { const float* p = cb + gid * 256; for (int c = 0; c < 256; ++c) s += p[c]; }
        else if (gid >= 32 && gid < 59) { const float* p = cb + (27 + (gid - 32)) * 256; for (int c = 0; c < 256; ++c) s += p[c]; }
        ksum[gid] = s;
    }
}

// ---------------- MFMA GEMM: C[M x NC] = A[M x K] @ Bp (fragment-packed) -----------
// Block: 256 thr / 4 waves; tile 128 rows x 64 cols; wave w -> rows w*32..w*32+31.
// A staged to LDS (fp32->bf16 cast if !ABF), padded [128][40] (2-way conflict: free).
template<int K, bool ABF, bool OUTBF>
__global__ __launch_bounds__(256)
void mfma_gemm(const void* __restrict__ Avoid, const unsigned short* __restrict__ Bp,
               unsigned short* __restrict__ Cb, float* __restrict__ Cf, int ldc)
{
    __shared__ unsigned short As[128][40];
    const int tid  = threadIdx.x;
    const int w    = tid >> 6, lane = tid & 63;
    const int r15  = lane & 15, g = lane >> 4;
    const long m0  = (long)blockIdx.y * 128;
    const int n0   = blockIdx.x * 64;
    const int nfrag0 = n0 >> 4;
    const int srow = tid >> 1;
    const int shalf = tid & 1;

    f32x4 acc[2][4];
    #pragma unroll
    for (int a_ = 0; a_ < 2; ++a_)
        #pragma unroll
        for (int b_ = 0; b_ < 4; ++b_) acc[a_][b_] = (f32x4){0.f, 0.f, 0.f, 0.f};

    for (int ks = 0; ks < K / 32; ++ks) {
        const int k0 = ks * 32;
        __syncthreads();
        if constexpr (ABF) {
            const unsigned short* A = (const unsigned short*)Avoid;
            const uint4 v0 = *(const uint4*)(A + (m0 + srow) * K + k0 + shalf * 16);
            const uint4 v1 = *(const uint4*)(A + (m0 + srow) * K + k0 + shalf * 16 + 8);
            *(uint4*)&As[srow][shalf * 16]     = v0;
            *(uint4*)&As[srow][shalf * 16 + 8] = v1;
        } else {
            const float* A = (const float*)Avoid + (m0 + srow) * K + k0 + shalf * 16;
            const float4 f0 = *(const float4*)(A + 0);
            const float4 f1 = *(const float4*)(A + 4);
            const float4 f2 = *(const float4*)(A + 8);
            const float4 f3 = *(const float4*)(A + 12);
            ushort4 h0 = { f2bf(f0.x), f2bf(f0.y), f2bf(f0.z), f2bf(f0.w) };
            ushort4 h1 = { f2bf(f1.x), f2bf(f1.y), f2bf(f1.z), f2bf(f1.w) };
            ushort4 h2 = { f2bf(f2.x), f2bf(f2.y), f2bf(f2.z), f2bf(f2.w) };
            ushort4 h3 = { f2bf(f3.x), f2bf(f3.y), f2bf(f3.z), f2bf(f3.w) };
            *(ushort4*)&As[srow][shalf * 16 + 0]  = h0;
            *(ushort4*)&As[srow][shalf * 16 + 4]  = h1;
            *(ushort4*)&As[srow][shalf * 16 + 8]  = h2;
            *(ushort4*)&As[srow][shalf * 16 + 12] = h3;
        }
        __syncthreads();
        bf16x8 af0 = *(const bf16x8*)&As[w * 32 + r15][g * 8];
        bf16x8 af1 = *(const bf16x8*)&As[w * 32 + 16 + r15][g * 8];
        #pragma unroll
        for (int nf = 0; nf < 4; ++nf) {
            const bf16x8 bf = *(const bf16x8*)(Bp + (((nfrag0 + nf) * (K / 32) + ks) * 64 + lane) * 8);
            acc[0][nf] = __builtin_amdgcn_mfma_f32_16x16x32_bf16(af0, bf, acc[0][nf], 0, 0, 0);
            acc[1][nf] = __builtin_amdgcn_mfma_f32_16x16x32_bf16(af1, bf, acc[1][nf], 0, 0, 0);
        }
    }
    // epilogue: C row = m0 + w*32 + fr*16 + g*4 + r, col = n0 + nf*16 + r15
    #pragma unroll
    for (int fr = 0; fr < 2; ++fr)
        #pragma unroll
        for (int nf = 0; nf < 4; ++nf)
            #pragma unroll
            for (int r = 0; r < 4; ++r) {
                const long row = m0 + w * 32 + fr * 16 + g * 4 + r;
                const int col = n0 + nf * 16 + r15;
                if constexpr (OUTBF) Cb[row * ldc + col] = f2bf(acc[fr][nf][r]);
                else                 Cf[row * ldc + col] = acc[fr][nf][r];
            }
}

// ---------------- MFMA y: y[N,27] = x @ Wq^T via 3-term bf16 split (near-fp32) -----
__global__ __launch_bounds__(256)
void mfma_y(const float* __restrict__ X, const unsigned short* __restrict__ Bqh,
            const unsigned short* __restrict__ Bql, float* __restrict__ y)
{
    __shared__ unsigned short Ah[128][40];
    __shared__ unsigned short Al[128][40];
    const int tid  = threadIdx.x;
    const int w    = tid >> 6, lane = tid & 63;
    const int r15  = lane & 15, g = lane >> 4;
    const long m0  = (long)blockIdx.y * 128;
    const int srow = tid >> 1;
    const int shalf = tid & 1;

    f32x4 acc[2][2];
    #pragma unroll
    for (int a_ = 0; a_ < 2; ++a_)
        #pragma unroll
        for (int b_ = 0; b_ < 2; ++b_) acc[a_][b_] = (f32x4){0.f, 0.f, 0.f, 0.f};

    for (int ks = 0; ks < 4; ++ks) {
        const int k0 = ks * 32;
        __syncthreads();
        {
            const float* A = X + (m0 + srow) * 128 + k0 + shalf * 16;
            float fs[16];
            const float4 f0 = *(const float4*)(A + 0);
            const float4 f1 = *(const float4*)(A + 4);
            const float4 f2 = *(const float4*)(A + 8);
            const float4 f3 = *(const float4*)(A + 12);
            fs[0]=f0.x; fs[1]=f0.y; fs[2]=f0.z; fs[3]=f0.w;
            fs[4]=f1.x; fs[5]=f1.y; fs[6]=f1.z; fs[7]=f1.w;
            fs[8]=f2.x; fs[9]=f2.y; fs[10]=f2.z; fs[11]=f2.w;
            fs[12]=f3.x; fs[13]=f3.y; fs[14]=f3.z; fs[15]=f3.w;
            #pragma unroll
            for (int q4 = 0; q4 < 4; ++q4) {
                ushort4 hq, lq;
                unsigned short h;
                h = f2bf(fs[q4*4+0]); hq.x = h; lq.x = f2bf(fs[q4*4+0] - bf2f(h));
                h = f2bf(fs[q4*4+1]); hq.y = h; lq.y = f2bf(fs[q4*4+1] - bf2f(h));
                h = f2bf(fs[q4*4+2]); hq.z = h; lq.z = f2bf(fs[q4*4+2] - bf2f(h));
                h = f2bf(fs[q4*4+3]); hq.w = h; lq.w = f2bf(fs[q4*4+3] - bf2f(h));
                *(ushort4*)&Ah[srow][shalf * 16 + q4 * 4] = hq;
                *(ushort4*)&Al[srow][shalf * 16 + q4 * 4] = lq;
            }
        }
        __syncthreads();
        bf16x8 ah0 = *(const bf16x8*)&Ah[w * 32 + r15][g * 8];
        bf16x8 ah1 = *(const bf16x8*)&Ah[w * 32 + 16 + r15][g * 8];
        bf16x8 al0 = *(const bf16x8*)&Al[w * 32 + r15][g * 8];
        bf16x8 al1 = *(const bf16x8*)&Al[w * 32 + 16 + r15][g * 8];
        #pragma unroll
        for (int nf = 0; nf < 2; ++nf) {
            const bf16x8 bh = *(const bf16x8*)(Bqh + ((nf * 4 + ks) * 64 + lane) * 8);
            const bf16x8 bl = *(const bf16x8*)(Bql + ((nf * 4 + ks) * 64 + lane) * 8);
            acc[0][nf] = __builtin_amdgcn_mfma_f32_16x16x32_bf16(ah0, bh, acc[0][nf], 0, 0, 0);
            acc[0][nf] = __builtin_amdgcn_mfma_f32_16x16x32_bf16(ah0, bl, acc[0][nf], 0, 0, 0);
            acc[0][nf] = __builtin_amdgcn_mfma_f32_16x16x32_bf16(al0, bh, acc[0][nf], 0, 0, 0);
            acc[1][nf] = __builtin_amdgcn_mfma_f32_16x16x32_bf16(ah1, bh, acc[1][nf], 0, 0, 0);
            acc[1][nf] = __builtin_amdgcn_mfma_f32_16x16x32_bf16(ah1, bl, acc[1][nf], 0, 0, 0);
            acc[1][nf] = __builtin_amdgcn_mfma_f32_16x16x32_bf16(al1, bh, acc[1][nf], 0, 0, 0);
        }
    }
    #pragma unroll
    for (int fr = 0; fr < 2; ++fr)
        #pragma unroll
        for (int nf = 0; nf < 2; ++nf)
            #pragma unroll
            for (int r = 0; r < 4; ++r) {
                const long row = m0 + w * 32 + fr * 16 + g * 4 + r;
                const int col = nf * 16 + r15;
                if (col < 27) y[row * 27 + col] = acc[fr][nf][r];
            }
}

// ---------------- column stats (sum, sumsq) over t1b [N,256] bf16 ------------------
__global__ __launch_bounds__(256)
void stats_t1(const unsigned short* __restrict__ t1b, float* __restrict__ stats)
{
    const int c = threadIdx.x;
    const long r0 = (long)blockIdx.x * 256;
    float s = 0.f, s2 = 0.f;
    #pragma unroll 4
    for (int r = 0; r < 256; ++r) {
        const float v = bf2f(t1b[(r0 + r) * 256 + c]);
        s += v; s2 += v * v;
    }
    atomicAdd(&stats[c], s);
    atomicAdd(&stats[256 + c], s2);
}

// ---------------- q_pre[n] = sum_k y[nbr[n,k], k]; accumulate scalar stats ---------
__global__ __launch_bounds__(256)
void qpre_kernel(const float* __restrict__ y, const int* __restrict__ nbr,
                 float* __restrict__ qpre, float* __restrict__ stats)
{
    __shared__ int snbr[256 * 27];
    __shared__ float red[8];
    const int tid = threadIdx.x;
    const long base = (long)blockIdx.x * 256;
    for (int j = tid; j < 256 * 27; j += 256) snbr[j] = nbr[base * 27 + j];
    __syncthreads();
    float q = 0.f;
    #pragma unroll
    for (int k = 0; k < 27; ++k) {
        const int idx = snbr[tid * 27 + k];
        q += y[(long)idx * 27 + k];
    }
    qpre[base + tid] = q;
    float s = q, s2 = q * q;
    #pragma unroll
    for (int off = 32; off > 0; off >>= 1) {
        s  += __shfl_xor(s, off);
        s2 += __shfl_xor(s2, off);
    }
    const int wid = tid >> 6;
    if ((tid & 63) == 0) { red[wid] = s; red[4 + wid] = s2; }
    __syncthreads();
    if (tid == 0) {
        atomicAdd(&stats[512], red[0] + red[1] + red[2] + red[3]);
        atomicAdd(&stats[513], red[4] + red[5] + red[6] + red[7]);
    }
}

// ---------------- gather/route: EXACT R4 body (386 us, VGPR 40, occ 65%) -----------
// FROZEN. Evidence: R5 (27-deep prefetch) 510us/VGPR136; R6 (+bounds cap) 2498us
// scratch spill; R7 (rolling-6) 649us/VGPR176; R8 (bf16 cbi load) 1318us with
// 3.2GB phantom writes = scratch. The naive load-then-consume loop with the fp32
// cb table is the only schedule hipcc compiles frugally. Do not touch.
__global__ __launch_bounds__(256, 4)
void gather_route(const unsigned short* __restrict__ t1b, const float* __restrict__ qpre,
                  const int* __restrict__ nbr, const float* __restrict__ cb,
                  const float* __restrict__ ksum, const float* __restrict__ stats,
                  const float* __restrict__ gv, const float* __restrict__ bvp,
                  const float* __restrict__ gq, const float* __restrict__ bq,
                  unsigned short* __restrict__ outpre, float inv_n)
{
    const long p  = (long)((blockIdx.x * 256 + threadIdx.x) >> 6);
    const int lane = threadIdx.x & 63;
    const int c4   = lane * 4;

    // per-lane v-BN affine coeffs (4 channels)
    float a[4], b[4];
    #pragma unroll
    for (int j = 0; j < 4; ++j) {
        const float mu  = stats[c4 + j] * inv_n;
        const float var = stats[256 + c4 + j] * inv_n - mu * mu;
        const float sc  = gv[c4 + j] * rsqrtf(var + EPSV);
        a[j] = sc;
        b[j] = bvp[c4 + j] - mu * sc;
    }
    // choice softmax: lanes 0..26 gather q of neighbors
    float s0 = 0.f, s1 = 0.f;
    int idx = 0;
    {
        const float muq  = stats[512] * inv_n;
        const float varq = stats[513] * inv_n - muq * muq;
        const float aq   = gq[0] * rsqrtf(varq + EPSV);
        const float bqc  = bq[0] - muq * aq;
        if (lane < 27) {
            idx = nbr[p * 27 + lane];
            const float qn = fmaxf(fmaf(qpre[idx], aq, bqc), 0.f);
            s0 = qn * ksum[lane];
            s1 = qn * ksum[32 + lane];
        }
    }
    #pragma unroll
    for (int off = 32; off > 0; off >>= 1) {
        s0 += __shfl_xor(s0, off);
        s1 += __shfl_xor(s1, off);
    }
    const float mm = fmaxf(s0, s1);
    const float e0 = __expf(s0 - mm);
    const float e1 = __expf(s1 - mm);
    const float c0 = e0 / (e0 + e1);
    const float c1 = 1.f - c0;

    float acc0[4] = {0, 0, 0, 0}, acc1[4] = {0, 0, 0, 0};
    #pragma unroll
    for (int k = 0; k < 27; ++k) {
        const int ik = __shfl(idx, k);
        const uint2 uu  = *(const uint2*)(t1b + (long)ik * 256 + c4);   // 4 bf16, 8B/lane
        const float4 w0 = *(const float4*)(cb + k * 256 + c4);
        const float4 w1 = *(const float4*)(cb + (27 + k) * 256 + c4);
        const float t0  = __uint_as_float(uu.x << 16);
        const float t1v = __uint_as_float(uu.x & 0xffff0000u);
        const float t2v = __uint_as_float(uu.y << 16);
        const float t3  = __uint_as_float(uu.y & 0xffff0000u);
        const float v0 = fmaxf(fmaf(t0,  a[0], b[0]), 0.f);
        const float v1 = fmaxf(fmaf(t1v, a[1], b[1]), 0.f);
        const float v2 = fmaxf(fmaf(t2v, a[2], b[2]), 0.f);
        const float v3 = fmaxf(fmaf(t3,  a[3], b[3]), 0.f);
        acc0[0] = fmaf(v0, w0.x, acc0[0]); acc0[1] = fmaf(v1, w0.y, acc0[1]);
        acc0[2] = fmaf(v2, w0.z, acc0[2]); acc0[3] = fmaf(v3, w0.w, acc0[3]);
        acc1[0] = fmaf(v0, w1.x, acc1[0]); acc1[1] = fmaf(v1, w1.y, acc1[1]);
        acc1[2] = fmaf(v2, w1.z, acc1[2]); acc1[3] = fmaf(v3, w1.w, acc1[3]);
    }
    ushort4 o;
    o.x = f2bf(fmaf(c0, acc0[0], c1 * acc1[0]));
    o.y = f2bf(fmaf(c0, acc0[1], c1 * acc1[1]));
    o.z = f2bf(fmaf(c0, acc0[2], c1 * acc1[2]));
    o.w = f2bf(fmaf(c0, acc0[3], c1 * acc1[3]));
    *(ushort4*)(outpre + p * 256 + c4) = o;
}

// ---------------- column stats over t2 [N,128] -------------------------------------
__global__ __launch_bounds__(128)
void stats_t2(const float* __restrict__ t2, float* __restrict__ stats)
{
    const int c = threadIdx.x;
    const long r0 = (long)blockIdx.x * 128;
    float s = 0.f, s2 = 0.f;
    #pragma unroll 4
    for (int r = 0; r < 128; ++r) {
        const float v = t2[(r0 + r) * 128 + c];
        s += v; s2 += v * v;
    }
    atomicAdd(&stats[544 + c], s);
    atomicAdd(&stats[672 + c], s2);
}

// ---------------- final BN+ReLU+residual (in-place on t2 == d_out) -----------------
__global__ __launch_bounds__(256)
void final_kernel(const float* __restrict__ t2, const float* __restrict__ x,
                  const float* __restrict__ stats,
                  const float* __restrict__ go, const float* __restrict__ bo,
                  float* __restrict__ out, long total4, float inv_n)
{
    const long i = (long)blockIdx.x * 256 + threadIdx.x;
    if (i >= total4) return;
    const int c4 = (int)((i * 4) & 127);
    float a[4], b[4];
    #pragma unroll
    for (int j = 0; j < 4; ++j) {
        const float mu  = stats[544 + c4 + j] * inv_n;
        const float var = stats[672 + c4 + j] * inv_n - mu * mu;
        const float sc  = go[c4 + j] * rsqrtf(var + EPSV);
        a[j] = sc;
        b[j] = bo[c4 + j] - mu * sc;
    }
    const float4 t  = *((const float4*)t2 + i);   // in-place safe
    const float4 xx = *((const float4*)x + i);
    float4 o;
    o.x = fmaxf(fmaf(t.x, a[0], b[0]), 0.f) + xx.x;
    o.y = fmaxf(fmaf(t.y, a[1], b[1]), 0.f) + xx.y;
    o.z = fmaxf(fmaf(t.z, a[2], b[2]), 0.f) + xx.z;
    o.w = fmaxf(fmaf(t.w, a[3], b[3]), 0.f) + xx.w;
    *((float4*)out + i) = o;
}

extern "C" void kernel_launch(void* const* d_in, const int* in_sizes, int n_in,
                              void* d_out, int out_size, void* d_ws, size_t ws_size,
                              hipStream_t stream)
{
    const float* x    = (const float*)d_in[0];
    const int*   nbr  = (const int*)d_in[1];
    const float* Wv   = (const float*)d_in[2];
    const float* gv   = (const float*)d_in[3];
    const float* bv   = (const float*)d_in[4];
    const float* Wq   = (const float*)d_in[5];
    const float* gq   = (const float*)d_in[6];
    const float* bq   = (const float*)d_in[7];
    const float* cb   = (const float*)d_in[8];
    const float* Wout = (const float*)d_in[9];
    const float* go   = (const float*)d_in[10];
    const float* bo   = (const float*)d_in[11];
    float* out = (float*)d_out;
    float* ws  = (float*)d_ws;

    const int N = in_sizes[0] / 128;
    const float inv_n = 1.f / (float)N;

    // workspace (floats): 65536 header + N*(128 + 27 + 1 + 128)  (~149 MB @ N=131072)
    float* ksum  = ws;                                     // 64
    float* stats = ws + 64;                                // 1024
    unsigned short* Bvp = (unsigned short*)(ws + 9216);    // 32768 us (16384 fl)
    unsigned short* Bop = (unsigned short*)(ws + 25600);   // 32768 us (16384 fl)
    unsigned short* Bqh = (unsigned short*)(ws + 41984);   // 4096 us (2048 fl)
    unsigned short* Bql = (unsigned short*)(ws + 44032);   // 4096 us (2048 fl)
    unsigned short* t1b = (unsigned short*)(ws + 65536);   // N*256 bf16
    float* y    = ws + 65536 + (long)N * 128;              // N*27
    float* qpre = y + (long)N * 27;                        // N
    unsigned short* outpre = (unsigned short*)(qpre + N);  // N*256 bf16
    float* t2   = out;                                     // N*128 in d_out

    hipLaunchKernelGGL(prep_kernel, dim3(192), dim3(256), 0, stream,
                       Wv, Wq, cb, Wout, ksum, Bvp, Bop, Bqh, Bql, stats);
    // t1b = bf16(x) @ Wv  (MFMA, 4 col-tiles of 64)
    mfma_gemm<128, false, true><<<dim3(4, N / 128), dim3(256), 0, stream>>>(
        (const void*)x, Bvp, t1b, (float*)nullptr, 256);
    // y = x @ Wq^T  (MFMA 3-term split, near-fp32)
    mfma_y<<<dim3(1, N / 128), dim3(256), 0, stream>>>(x, Bqh, Bql, y);
    hipLaunchKernelGGL(stats_t1, dim3(N / 256), dim3(256), 0, stream, t1b, stats);
    hipLaunchKernelGGL(qpre_kernel, dim3(N / 256), dim3(256), 0, stream, y, nbr, qpre, stats);
    hipLaunchKernelGGL(gather_route, dim3(N / 4), dim3(256), 0, stream,
                       t1b, qpre, nbr, cb, ksum, stats, gv, bv, gq, bq, outpre, inv_n);
    // t2 = outpre @ Wout  (MFMA, 2 col-tiles of 64)
    mfma_gemm<256, true, false><<<dim3(2, N / 128), dim3(256), 0, stream>>>(
        (const void*)outpre, Bop, (unsigned short*)nullptr, t2, 128);
    hipLaunchKernelGGL(stats_t2, dim3(N / 128), dim3(128), 0, stream, t2, stats);
    hipLaunchKernelGGL(final_kernel, dim3((unsigned)(((long)N * 128 / 4 + 255) / 256)), dim3(256), 0, stream,
                       t2, x, stats, go, bo, out, (long)N * 128 / 4, inv_n);
}

// Round 10
// 731.859 us; speedup vs baseline: 2.2781x; 1.0110x over previous
//
#include <hip/hip_runtime.h>
#include <math.h>

#define EPSV 1e-5f

typedef __attribute__((ext_vector_type(8))) short bf16x8;
typedef __attribute__((ext_vector_type(4))) float f32x4;

// ---- bf16 helpers (round-to-nearest-even pack, bit-shift unpack) ------------------
__device__ __forceinline__ unsigned short f2bf(float f) {
    unsigned u = __float_as_uint(f);
    u += 0x7fffu + ((u >> 16) & 1u);
    return (unsigned short)(u >> 16);
}
__device__ __forceinline__ float bf2f(unsigned short h) {
    return __uint_as_float(((unsigned)h) << 16);
}

// ---------------- prep: ksum, fragment-packed weights, zero stats ------------------
// Fragment packing (for mfma_f32_16x16x32_bf16): frag(nf, ks) is 64 lanes x 8 vals;
// lane l, elem i holds B[k][n] with k = ks*32 + (l>>4)*8 + i, n = nf*16 + (l&15).
// Same (g,i)->k bijection is used for A frags, so the K-reduction is exact.
__global__ __launch_bounds__(256)
void prep_kernel(const float* __restrict__ Wv, const float* __restrict__ Wq,
                 const float* __restrict__ cb, const float* __restrict__ Wout,
                 float* __restrict__ ksum,
                 unsigned short* __restrict__ Bvp, unsigned short* __restrict__ Bop,
                 unsigned short* __restrict__ Bqh, unsigned short* __restrict__ Bql,
                 float* __restrict__ stats)
{
    const long gid = (long)blockIdx.x * 256 + threadIdx.x;
    // Bvp: Wv [128][256], K=128 (4 ksteps), 16 col-frags -> 32768 bf16
    if (gid < 32768) {
        const int i = (int)(gid & 7);
        const int l = (int)((gid >> 3) & 63);
        const int rest = (int)(gid >> 9);
        const int ks = rest & 3, nf = rest >> 2;
        const int k = ks * 32 + ((l >> 4) << 3) + i;
        const int n = nf * 16 + (l & 15);
        Bvp[gid] = f2bf(Wv[k * 256 + n]);
    }
    // Bop: Wout [256][128], K=256 (8 ksteps), 8 col-frags -> 32768 bf16
    if (gid < 32768) {
        const int i = (int)(gid & 7);
        const int l = (int)((gid >> 3) & 63);
        const int rest = (int)(gid >> 9);
        const int ks = rest & 7, nf = rest >> 3;
        const int k = ks * 32 + ((l >> 4) << 3) + i;
        const int n = nf * 16 + (l & 15);
        Bop[gid] = f2bf(Wout[k * 128 + n]);
    }
    // Bqh/Bql: Wq[n][k] split hi/lo, K=128, 2 col-frags (cols >=27 zero) -> 4096 each
    if (gid < 4096) {
        const int i = (int)(gid & 7);
        const int l = (int)((gid >> 3) & 63);
        const int rest = (int)(gid >> 9);
        const int ks = rest & 3, nf = rest >> 2;
        const int k = ks * 32 + ((l >> 4) << 3) + i;
        const int n = nf * 16 + (l & 15);
        const float w = (n < 27) ? Wq[n * 128 + k] : 0.f;
        const unsigned short h = f2bf(w);
        Bqh[gid] = h;
        Bql[gid] = f2bf(w - bf2f(h));
    }
    if (gid < 1024) stats[gid] = 0.f;
    if (gid < 64) {
        float s = 0.f;
        if (gid < 27) { const float* p = cb + gid * 256; for (int c = 0; c < 256; ++c) s += p[c]; }
        else if (gid >= 32 && gid < 59) { const float* p = cb + (27 + (gid - 32)) * 256; for (int c = 0; c < 256; ++c) s += p[c]; }
        ksum[gid] = s;
    }
}

// ---------------- MFMA GEMM: C[M x NC] = A[M x K] @ Bp (fragment-packed) -----------
// Block: 256 thr / 4 waves; tile 128 rows x NF*16 cols; wave w -> rows w*32..+31.
// A staged to LDS (fp32->bf16 cast if !ABF), padded [128][40] (2-way conflict: free).
// NF=8 (128-col tile) halves A re-reads vs NF=4.
template<int K, int NF, bool ABF, bool OUTBF>
__global__ __launch_bounds__(256)
void mfma_gemm(const void* __restrict__ Avoid, const unsigned short* __restrict__ Bp,
               unsigned short* __restrict__ Cb, float* __restrict__ Cf, int ldc)
{
    __shared__ unsigned short As[128][40];
    const int tid  = threadIdx.x;
    const int w    = tid >> 6, lane = tid & 63;
    const int r15  = lane & 15, g = lane >> 4;
    const long m0  = (long)blockIdx.y * 128;
    const int n0   = blockIdx.x * (NF * 16);
    const int nfrag0 = n0 >> 4;
    const int srow = tid >> 1;
    const int shalf = tid & 1;

    f32x4 acc[2][NF];
    #pragma unroll
    for (int a_ = 0; a_ < 2; ++a_)
        #pragma unroll
        for (int b_ = 0; b_ < NF; ++b_) acc[a_][b_] = (f32x4){0.f, 0.f, 0.f, 0.f};

    for (int ks = 0; ks < K / 32; ++ks) {
        const int k0 = ks * 32;
        __syncthreads();
        if constexpr (ABF) {
            const unsigned short* A = (const unsigned short*)Avoid;
            const uint4 v0 = *(const uint4*)(A + (m0 + srow) * K + k0 + shalf * 16);
            const uint4 v1 = *(const uint4*)(A + (m0 + srow) * K + k0 + shalf * 16 + 8);
            *(uint4*)&As[srow][shalf * 16]     = v0;
            *(uint4*)&As[srow][shalf * 16 + 8] = v1;
        } else {
            const float* A = (const float*)Avoid + (m0 + srow) * K + k0 + shalf * 16;
            const float4 f0 = *(const float4*)(A + 0);
            const float4 f1 = *(const float4*)(A + 4);
            const float4 f2 = *(const float4*)(A + 8);
            const float4 f3 = *(const float4*)(A + 12);
            ushort4 h0 = { f2bf(f0.x), f2bf(f0.y), f2bf(f0.z), f2bf(f0.w) };
            ushort4 h1 = { f2bf(f1.x), f2bf(f1.y), f2bf(f1.z), f2bf(f1.w) };
            ushort4 h2 = { f2bf(f2.x), f2bf(f2.y), f2bf(f2.z), f2bf(f2.w) };
            ushort4 h3 = { f2bf(f3.x), f2bf(f3.y), f2bf(f3.z), f2bf(f3.w) };
            *(ushort4*)&As[srow][shalf * 16 + 0]  = h0;
            *(ushort4*)&As[srow][shalf * 16 + 4]  = h1;
            *(ushort4*)&As[srow][shalf * 16 + 8]  = h2;
            *(ushort4*)&As[srow][shalf * 16 + 12] = h3;
        }
        __syncthreads();
        bf16x8 af0 = *(const bf16x8*)&As[w * 32 + r15][g * 8];
        bf16x8 af1 = *(const bf16x8*)&As[w * 32 + 16 + r15][g * 8];
        #pragma unroll
        for (int nf = 0; nf < NF; ++nf) {
            const bf16x8 bf = *(const bf16x8*)(Bp + (((nfrag0 + nf) * (K / 32) + ks) * 64 + lane) * 8);
            acc[0][nf] = __builtin_amdgcn_mfma_f32_16x16x32_bf16(af0, bf, acc[0][nf], 0, 0, 0);
            acc[1][nf] = __builtin_amdgcn_mfma_f32_16x16x32_bf16(af1, bf, acc[1][nf], 0, 0, 0);
        }
    }
    // epilogue: C row = m0 + w*32 + fr*16 + g*4 + r, col = n0 + nf*16 + r15
    #pragma unroll
    for (int fr = 0; fr < 2; ++fr)
        #pragma unroll
        for (int nf = 0; nf < NF; ++nf)
            #pragma unroll
            for (int r = 0; r < 4; ++r) {
                const long row = m0 + w * 32 + fr * 16 + g * 4 + r;
                const int col = n0 + nf * 16 + r15;
                if constexpr (OUTBF) Cb[row * ldc + col] = f2bf(acc[fr][nf][r]);
                else                 Cf[row * ldc + col] = acc[fr][nf][r];
            }
}

// ---------------- MFMA y: y[N,27] = x @ Wq^T via 3-term bf16 split (near-fp32) -----
__global__ __launch_bounds__(256)
void mfma_y(const float* __restrict__ X, const unsigned short* __restrict__ Bqh,
            const unsigned short* __restrict__ Bql, float* __restrict__ y)
{
    __shared__ unsigned short Ah[128][40];
    __shared__ unsigned short Al[128][40];
    const int tid  = threadIdx.x;
    const int w    = tid >> 6, lane = tid & 63;
    const int r15  = lane & 15, g = lane >> 4;
    const long m0  = (long)blockIdx.y * 128;
    const int srow = tid >> 1;
    const int shalf = tid & 1;

    f32x4 acc[2][2];
    #pragma unroll
    for (int a_ = 0; a_ < 2; ++a_)
        #pragma unroll
        for (int b_ = 0; b_ < 2; ++b_) acc[a_][b_] = (f32x4){0.f, 0.f, 0.f, 0.f};

    for (int ks = 0; ks < 4; ++ks) {
        const int k0 = ks * 32;
        __syncthreads();
        {
            const float* A = X + (m0 + srow) * 128 + k0 + shalf * 16;
            float fs[16];
            const float4 f0 = *(const float4*)(A + 0);
            const float4 f1 = *(const float4*)(A + 4);
            const float4 f2 = *(const float4*)(A + 8);
            const float4 f3 = *(const float4*)(A + 12);
            fs[0]=f0.x; fs[1]=f0.y; fs[2]=f0.z; fs[3]=f0.w;
            fs[4]=f1.x; fs[5]=f1.y; fs[6]=f1.z; fs[7]=f1.w;
            fs[8]=f2.x; fs[9]=f2.y; fs[10]=f2.z; fs[11]=f2.w;
            fs[12]=f3.x; fs[13]=f3.y; fs[14]=f3.z; fs[15]=f3.w;
            #pragma unroll
            for (int q4 = 0; q4 < 4; ++q4) {
                ushort4 hq, lq;
                unsigned short h;
                h = f2bf(fs[q4*4+0]); hq.x = h; lq.x = f2bf(fs[q4*4+0] - bf2f(h));
                h = f2bf(fs[q4*4+1]); hq.y = h; lq.y = f2bf(fs[q4*4+1] - bf2f(h));
                h = f2bf(fs[q4*4+2]); hq.z = h; lq.z = f2bf(fs[q4*4+2] - bf2f(h));
                h = f2bf(fs[q4*4+3]); hq.w = h; lq.w = f2bf(fs[q4*4+3] - bf2f(h));
                *(ushort4*)&Ah[srow][shalf * 16 + q4 * 4] = hq;
                *(ushort4*)&Al[srow][shalf * 16 + q4 * 4] = lq;
            }
        }
        __syncthreads();
        bf16x8 ah0 = *(const bf16x8*)&Ah[w * 32 + r15][g * 8];
        bf16x8 ah1 = *(const bf16x8*)&Ah[w * 32 + 16 + r15][g * 8];
        bf16x8 al0 = *(const bf16x8*)&Al[w * 32 + r15][g * 8];
        bf16x8 al1 = *(const bf16x8*)&Al[w * 32 + 16 + r15][g * 8];
        #pragma unroll
        for (int nf = 0; nf < 2; ++nf) {
            const bf16x8 bh = *(const bf16x8*)(Bqh + ((nf * 4 + ks) * 64 + lane) * 8);
            const bf16x8 bl = *(const bf16x8*)(Bql + ((nf * 4 + ks) * 64 + lane) * 8);
            acc[0][nf] = __builtin_amdgcn_mfma_f32_16x16x32_bf16(ah0, bh, acc[0][nf], 0, 0, 0);
            acc[0][nf] = __builtin_amdgcn_mfma_f32_16x16x32_bf16(ah0, bl, acc[0][nf], 0, 0, 0);
            acc[0][nf] = __builtin_amdgcn_mfma_f32_16x16x32_bf16(al0, bh, acc[0][nf], 0, 0, 0);
            acc[1][nf] = __builtin_amdgcn_mfma_f32_16x16x32_bf16(ah1, bh, acc[1][nf], 0, 0, 0);
            acc[1][nf] = __builtin_amdgcn_mfma_f32_16x16x32_bf16(ah1, bl, acc[1][nf], 0, 0, 0);
            acc[1][nf] = __builtin_amdgcn_mfma_f32_16x16x32_bf16(al1, bh, acc[1][nf], 0, 0, 0);
        }
    }
    #pragma unroll
    for (int fr = 0; fr < 2; ++fr)
        #pragma unroll
        for (int nf = 0; nf < 2; ++nf)
            #pragma unroll
            for (int r = 0; r < 4; ++r) {
                const long row = m0 + w * 32 + fr * 16 + g * 4 + r;
                const int col = nf * 16 + r15;
                if (col < 27) y[row * 27 + col] = acc[fr][nf][r];
            }
}

// ---------------- column stats over t1b [N,256] bf16, coalesced uint2 --------------
// Wave w covers rows r0+w*64..+63; lane owns 4 cols (uint2 = 512B/wave-row, full
// coalescing vs the old 2B-per-thread column walk). LDS float4 combine, then one
// atomicAdd pair per column per block (same atomic count as before).
__global__ __launch_bounds__(256)
void stats_t1(const unsigned short* __restrict__ t1b, float* __restrict__ stats)
{
    __shared__ float red[8][256];
    const int tid  = threadIdx.x;
    const int lane = tid & 63, w = tid >> 6;
    const int c4   = lane * 4;
    const long r0  = (long)blockIdx.x * 256 + w * 64;
    float s0 = 0, s1 = 0, s2 = 0, s3 = 0, q0 = 0, q1 = 0, q2 = 0, q3 = 0;
    #pragma unroll 4
    for (int r = 0; r < 64; ++r) {
        const uint2 u = *(const uint2*)(t1b + (r0 + r) * 256 + c4);
        const float v0 = __uint_as_float(u.x << 16);
        const float v1 = __uint_as_float(u.x & 0xffff0000u);
        const float v2 = __uint_as_float(u.y << 16);
        const float v3 = __uint_as_float(u.y & 0xffff0000u);
        s0 += v0; s1 += v1; s2 += v2; s3 += v3;
        q0 += v0 * v0; q1 += v1 * v1; q2 += v2 * v2; q3 += v3 * v3;
    }
    *(float4*)&red[w][c4]     = make_float4(s0, s1, s2, s3);
    *(float4*)&red[4 + w][c4] = make_float4(q0, q1, q2, q3);
    __syncthreads();
    atomicAdd(&stats[tid],       red[0][tid] + red[1][tid] + red[2][tid] + red[3][tid]);
    atomicAdd(&stats[256 + tid], red[4][tid] + red[5][tid] + red[6][tid] + red[7][tid]);
}

// ---------------- q_pre[n] = sum_k y[nbr[n,k], k]; accumulate scalar stats ---------
__global__ __launch_bounds__(256)
void qpre_kernel(const float* __restrict__ y, const int* __restrict__ nbr,
                 float* __restrict__ qpre, float* __restrict__ stats)
{
    __shared__ int snbr[256 * 27];
    __shared__ float red[8];
    const int tid = threadIdx.x;
    const long base = (long)blockIdx.x * 256;
    for (int j = tid; j < 256 * 27; j += 256) snbr[j] = nbr[base * 27 + j];
    __syncthreads();
    float q = 0.f;
    #pragma unroll
    for (int k = 0; k < 27; ++k) {
        const int idx = snbr[tid * 27 + k];
        q += y[(long)idx * 27 + k];
    }
    qpre[base + tid] = q;
    float s = q, s2 = q * q;
    #pragma unroll
    for (int off = 32; off > 0; off >>= 1) {
        s  += __shfl_xor(s, off);
        s2 += __shfl_xor(s2, off);
    }
    const int wid = tid >> 6;
    if ((tid & 63) == 0) { red[wid] = s; red[4 + wid] = s2; }
    __syncthreads();
    if (tid == 0) {
        atomicAdd(&stats[512], red[0] + red[1] + red[2] + red[3]);
        atomicAdd(&stats[513], red[4] + red[5] + red[6] + red[7]);
    }
}

// ---------------- gather/route: EXACT R4 body (386 us, VGPR 40, occ 65%) -----------
// FROZEN. Evidence: R5 (27-deep prefetch) 510us/VGPR136; R6 (+bounds cap) 2498us
// scratch spill; R7 (rolling-6) 649us/VGPR176; R8 (bf16 cbi load) 1318us with
// 3.2GB phantom writes = scratch. The naive load-then-consume loop with the fp32
// cb table is the only schedule hipcc compiles frugally. Do not touch.
__global__ __launch_bounds__(256, 4)
void gather_route(const unsigned short* __restrict__ t1b, const float* __restrict__ qpre,
                  const int* __restrict__ nbr, const float* __restrict__ cb,
                  const float* __restrict__ ksum, const float* __restrict__ stats,
                  const float* __restrict__ gv, const float* __restrict__ bvp,
                  const float* __restrict__ gq, const float* __restrict__ bq,
                  unsigned short* __restrict__ outpre, float inv_n)
{
    const long p  = (long)((blockIdx.x * 256 + threadIdx.x) >> 6);
    const int lane = threadIdx.x & 63;
    const int c4   = lane * 4;

    // per-lane v-BN affine coeffs (4 channels)
    float a[4], b[4];
    #pragma unroll
    for (int j = 0; j < 4; ++j) {
        const float mu  = stats[c4 + j] * inv_n;
        const float var = stats[256 + c4 + j] * inv_n - mu * mu;
        const float sc  = gv[c4 + j] * rsqrtf(var + EPSV);
        a[j] = sc;
        b[j] = bvp[c4 + j] - mu * sc;
    }
    // choice softmax: lanes 0..26 gather q of neighbors
    float s0 = 0.f, s1 = 0.f;
    int idx = 0;
    {
        const float muq  = stats[512] * inv_n;
        const float varq = stats[513] * inv_n - muq * muq;
        const float aq   = gq[0] * rsqrtf(varq + EPSV);
        const float bqc  = bq[0] - muq * aq;
        if (lane < 27) {
            idx = nbr[p * 27 + lane];
            const float qn = fmaxf(fmaf(qpre[idx], aq, bqc), 0.f);
            s0 = qn * ksum[lane];
            s1 = qn * ksum[32 + lane];
        }
    }
    #pragma unroll
    for (int off = 32; off > 0; off >>= 1) {
        s0 += __shfl_xor(s0, off);
        s1 += __shfl_xor(s1, off);
    }
    const float mm = fmaxf(s0, s1);
    const float e0 = __expf(s0 - mm);
    const float e1 = __expf(s1 - mm);
    const float c0 = e0 / (e0 + e1);
    const float c1 = 1.f - c0;

    float acc0[4] = {0, 0, 0, 0}, acc1[4] = {0, 0, 0, 0};
    #pragma unroll
    for (int k = 0; k < 27; ++k) {
        const int ik = __shfl(idx, k);
        const uint2 uu  = *(const uint2*)(t1b + (long)ik * 256 + c4);   // 4 bf16, 8B/lane
        const float4 w0 = *(const float4*)(cb + k * 256 + c4);
        const float4 w1 = *(const float4*)(cb + (27 + k) * 256 + c4);
        const float t0  = __uint_as_float(uu.x << 16);
        const float t1v = __uint_as_float(uu.x & 0xffff0000u);
        const float t2v = __uint_as_float(uu.y << 16);
        const float t3  = __uint_as_float(uu.y & 0xffff0000u);
        const float v0 = fmaxf(fmaf(t0,  a[0], b[0]), 0.f);
        const float v1 = fmaxf(fmaf(t1v, a[1], b[1]), 0.f);
        const float v2 = fmaxf(fmaf(t2v, a[2], b[2]), 0.f);
        const float v3 = fmaxf(fmaf(t3,  a[3], b[3]), 0.f);
        acc0[0] = fmaf(v0, w0.x, acc0[0]); acc0[1] = fmaf(v1, w0.y, acc0[1]);
        acc0[2] = fmaf(v2, w0.z, acc0[2]); acc0[3] = fmaf(v3, w0.w, acc0[3]);
        acc1[0] = fmaf(v0, w1.x, acc1[0]); acc1[1] = fmaf(v1, w1.y, acc1[1]);
        acc1[2] = fmaf(v2, w1.z, acc1[2]); acc1[3] = fmaf(v3, w1.w, acc1[3]);
    }
    ushort4 o;
    o.x = f2bf(fmaf(c0, acc0[0], c1 * acc1[0]));
    o.y = f2bf(fmaf(c0, acc0[1], c1 * acc1[1]));
    o.z = f2bf(fmaf(c0, acc0[2], c1 * acc1[2]));
    o.w = f2bf(fmaf(c0, acc0[3], c1 * acc1[3]));
    *(ushort4*)(outpre + p * 256 + c4) = o;
}

// ---------------- column stats over t2 [N,128] -------------------------------------
__global__ __launch_bounds__(128)
void stats_t2(const float* __restrict__ t2, float* __restrict__ stats)
{
    const int c = threadIdx.x;
    const long r0 = (long)blockIdx.x * 128;
    float s = 0.f, s2 = 0.f;
    #pragma unroll 4
    for (int r = 0; r < 128; ++r) {
        const float v = t2[(r0 + r) * 128 + c];
        s += v; s2 += v * v;
    }
    atomicAdd(&stats[544 + c], s);
    atomicAdd(&stats[672 + c], s2);
}

// ---------------- final BN+ReLU+residual (in-place on t2 == d_out) -----------------
__global__ __launch_bounds__(256)
void final_kernel(const float* __restrict__ t2, const float* __restrict__ x,
                  const float* __restrict__ stats,
                  const float* __restrict__ go, const float* __restrict__ bo,
                  float* __restrict__ out, long total4, float inv_n)
{
    const long i = (long)blockIdx.x * 256 + threadIdx.x;
    if (i >= total4) return;
    const int c4 = (int)((i * 4) & 127);
    float a[4], b[4];
    #pragma unroll
    for (int j = 0; j < 4; ++j) {
        const float mu  = stats[544 + c4 + j] * inv_n;
        const float var = stats[672 + c4 + j] * inv_n - mu * mu;
        const float sc  = go[c4 + j] * rsqrtf(var + EPSV);
        a[j] = sc;
        b[j] = bo[c4 + j] - mu * sc;
    }
    const float4 t  = *((const float4*)t2 + i);   // in-place safe
    const float4 xx = *((const float4*)x + i);
    float4 o;
    o.x = fmaxf(fmaf(t.x, a[0], b[0]), 0.f) + xx.x;
    o.y = fmaxf(fmaf(t.y, a[1], b[1]), 0.f) + xx.y;
    o.z = fmaxf(fmaf(t.z, a[2], b[2]), 0.f) + xx.z;
    o.w = fmaxf(fmaf(t.w, a[3], b[3]), 0.f) + xx.w;
    *((float4*)out + i) = o;
}

extern "C" void kernel_launch(void* const* d_in, const int* in_sizes, int n_in,
                              void* d_out, int out_size, void* d_ws, size_t ws_size,
                              hipStream_t stream)
{
    const float* x    = (const float*)d_in[0];
    const int*   nbr  = (const int*)d_in[1];
    const float* Wv   = (const float*)d_in[2];
    const float* gv   = (const float*)d_in[3];
    const float* bv   = (const float*)d_in[4];
    const float* Wq   = (const float*)d_in[5];
    const float* gq   = (const float*)d_in[6];
    const float* bq   = (const float*)d_in[7];
    const float* cb   = (const float*)d_in[8];
    const float* Wout = (const float*)d_in[9];
    const float* go   = (const float*)d_in[10];
    const float* bo   = (const float*)d_in[11];
    float* out = (float*)d_out;
    float* ws  = (float*)d_ws;

    const int N = in_sizes[0] / 128;
    const float inv_n = 1.f / (float)N;

    // workspace (floats): 65536 header + N*(128 + 27 + 1 + 128)  (~149 MB @ N=131072)
    float* ksum  = ws;                                     // 64
    float* stats = ws + 64;                                // 1024
    unsigned short* Bvp = (unsigned short*)(ws + 9216);    // 32768 us (16384 fl)
    unsigned short* Bop = (unsigned short*)(ws + 25600);   // 32768 us (16384 fl)
    unsigned short* Bqh = (unsigned short*)(ws + 41984);   // 4096 us (2048 fl)
    unsigned short* Bql = (unsigned short*)(ws + 44032);   // 4096 us (2048 fl)
    unsigned short* t1b = (unsigned short*)(ws + 65536);   // N*256 bf16
    float* y    = ws + 65536 + (long)N * 128;              // N*27
    float* qpre = y + (long)N * 27;                        // N
    unsigned short* outpre = (unsigned short*)(qpre + N);  // N*256 bf16
    float* t2   = out;                                     // N*128 in d_out

    hipLaunchKernelGGL(prep_kernel, dim3(192), dim3(256), 0, stream,
                       Wv, Wq, cb, Wout, ksum, Bvp, Bop, Bqh, Bql, stats);
    // t1b = bf16(x) @ Wv  (MFMA, 2 col-tiles of 128)
    mfma_gemm<128, 8, false, true><<<dim3(2, N / 128), dim3(256), 0, stream>>>(
        (const void*)x, Bvp, t1b, (float*)nullptr, 256);
    // y = x @ Wq^T  (MFMA 3-term split, near-fp32)
    mfma_y<<<dim3(1, N / 128), dim3(256), 0, stream>>>(x, Bqh, Bql, y);
    hipLaunchKernelGGL(stats_t1, dim3(N / 256), dim3(256), 0, stream, t1b, stats);
    hipLaunchKernelGGL(qpre_kernel, dim3(N / 256), dim3(256), 0, stream, y, nbr, qpre, stats);
    hipLaunchKernelGGL(gather_route, dim3(N / 4), dim3(256), 0, stream,
                       t1b, qpre, nbr, cb, ksum, stats, gv, bv, gq, bq, outpre, inv_n);
    // t2 = outpre @ Wout  (MFMA, single 128-col tile)
    mfma_gemm<256, 8, true, false><<<dim3(1, N / 128), dim3(256), 0, stream>>>(
        (const void*)outpre, Bop, (unsigned short*)nullptr, t2, 128);
    hipLaunchKernelGGL(stats_t2, dim3(N / 128), dim3(128), 0, stream, t2, stats);
    hipLaunchKernelGGL(final_kernel, dim3((unsigned)(((long)N * 128 / 4 + 255) / 256)), dim3(256), 0, stream,
                       t2, x, stats, go, bo, out, (long)N * 128 / 4, inv_n);
}